// Round 1
// baseline (6737.700 us; speedup 1.0000x reference)
//
#include <hip/hip_runtime.h>

#define DIM 256               // feature dim
#define LANES_PER_EDGE 64     // one wave per edge, each lane does a float4

// One wavefront (64 lanes) processes one edge: gather a 256-f32 row from x
// at row src[e] (coalesced, 16B/lane) and atomicAdd into row dst[e] of out.
// RELU_GATHER applies relu to the gathered value (used for hop 2, which
// consumes relu(hop1 sums) without a separate pass).
template <bool RELU_GATHER>
__global__ void scatter_rows(const float* __restrict__ x,
                             const int* __restrict__ src,
                             const int* __restrict__ dst,
                             float* __restrict__ out,
                             int E) {
    long long tid = (long long)blockIdx.x * blockDim.x + threadIdx.x;
    int e = (int)(tid >> 6);         // wave index == edge index
    int lane = (int)(tid & 63);
    if (e >= E) return;

    int s = src[e];                  // wave-uniform broadcast load
    int t = dst[e];

    const float4* row = (const float4*)(x + (long long)s * DIM);
    float4 v = row[lane];
    if (RELU_GATHER) {
        v.x = fmaxf(v.x, 0.0f);
        v.y = fmaxf(v.y, 0.0f);
        v.z = fmaxf(v.z, 0.0f);
        v.w = fmaxf(v.w, 0.0f);
    }
    float* o = out + (long long)t * DIM + (long long)lane * 4;
    atomicAdd(o + 0, v.x);
    atomicAdd(o + 1, v.y);
    atomicAdd(o + 2, v.z);
    atomicAdd(o + 3, v.w);
}

__global__ void relu_inplace_f4(float4* __restrict__ x, long long n4) {
    long long stride = (long long)gridDim.x * blockDim.x;
    for (long long i = (long long)blockIdx.x * blockDim.x + threadIdx.x; i < n4; i += stride) {
        float4 v = x[i];
        v.x = fmaxf(v.x, 0.0f);
        v.y = fmaxf(v.y, 0.0f);
        v.z = fmaxf(v.z, 0.0f);
        v.w = fmaxf(v.w, 0.0f);
        x[i] = v;
    }
}

extern "C" void kernel_launch(void* const* d_in, const int* in_sizes, int n_in,
                              void* d_out, int out_size, void* d_ws, size_t ws_size,
                              hipStream_t stream) {
    const float* x_paper = (const float*)d_in[0];
    // d_in[1] = x_author (unused except for author count)
    const int* e_pa_src = (const int*)d_in[2];
    const int* e_pa_dst = (const int*)d_in[3];
    const int* e_ap_src = (const int*)d_in[4];
    const int* e_ap_dst = (const int*)d_in[5];

    const int n_author = in_sizes[1] / DIM;   // 100000
    const int E1 = in_sizes[2];               // 1000000
    const int E2 = in_sizes[4];               // 1000000

    float* x_a1 = (float*)d_ws;               // N_A * 256 f32 = 102.4 MB
    float* x_p2 = (float*)d_out;              // N_P * 256 f32 = 204.8 MB

    const size_t a1_bytes = (size_t)n_author * DIM * sizeof(float);
    const size_t out_bytes = (size_t)out_size * sizeof(float);

    hipMemsetAsync(x_a1, 0, a1_bytes, stream);
    hipMemsetAsync(x_p2, 0, out_bytes, stream);

    const int block = 256;                    // 4 edges per block
    {
        long long threads = (long long)E1 * LANES_PER_EDGE;
        int grid = (int)((threads + block - 1) / block);
        scatter_rows<false><<<grid, block, 0, stream>>>(x_paper, e_pa_src, e_pa_dst, x_a1, E1);
    }
    {
        long long threads = (long long)E2 * LANES_PER_EDGE;
        int grid = (int)((threads + block - 1) / block);
        scatter_rows<true><<<grid, block, 0, stream>>>(x_a1, e_ap_src, e_ap_dst, x_p2, E2);
    }
    {
        long long n4 = (long long)out_size / 4;
        int grid = 2048;
        relu_inplace_f4<<<grid, block, 0, stream>>>((float4*)d_out, n4);
    }
}

// Round 2
// 573.441 us; speedup vs baseline: 11.7496x; 11.7496x over previous
//
#include <hip/hip_runtime.h>

#define DIM 256
#define SCAN_T 256
#define SCAN_I 8
#define SCAN_TILE (SCAN_T * SCAN_I)

// ---------------- CSR build ----------------

__global__ void hist_kernel(const int* __restrict__ dst, int* __restrict__ counts, int E) {
    int stride = gridDim.x * blockDim.x;
    for (int e = blockIdx.x * blockDim.x + threadIdx.x; e < E; e += stride)
        atomicAdd(&counts[dst[e]], 1);
}

// Tiled exclusive scan, 3 kernels. n <= SCAN_T*SCAN_TILE (here 200001 << 524288).
__global__ void scan_blocks(const int* __restrict__ in, int* __restrict__ out,
                            int* __restrict__ partials, int n) {
    __shared__ int sd[SCAN_T];
    int base = blockIdx.x * SCAN_TILE + threadIdx.x * SCAN_I;
    int v[SCAN_I];
    int tsum = 0;
#pragma unroll
    for (int j = 0; j < SCAN_I; ++j) {
        int idx = base + j;
        v[j] = (idx < n) ? in[idx] : 0;
        tsum += v[j];
    }
    sd[threadIdx.x] = tsum;
    __syncthreads();
    int acc = tsum;
    for (int ofs = 1; ofs < SCAN_T; ofs <<= 1) {
        int y = (threadIdx.x >= ofs) ? sd[threadIdx.x - ofs] : 0;
        __syncthreads();
        acc += y;
        sd[threadIdx.x] = acc;
        __syncthreads();
    }
    int excl = acc - tsum;
    if (threadIdx.x == SCAN_T - 1) partials[blockIdx.x] = acc;  // block total (inclusive)
    int run = excl;
#pragma unroll
    for (int j = 0; j < SCAN_I; ++j) {
        int idx = base + j;
        if (idx < n) out[idx] = run;
        run += v[j];
    }
}

__global__ void scan_single(int* __restrict__ data, int n) {   // n <= SCAN_T
    __shared__ int sd[SCAN_T];
    int x = (threadIdx.x < n) ? data[threadIdx.x] : 0;
    sd[threadIdx.x] = x;
    __syncthreads();
    int acc = x;
    for (int ofs = 1; ofs < SCAN_T; ofs <<= 1) {
        int y = (threadIdx.x >= ofs) ? sd[threadIdx.x - ofs] : 0;
        __syncthreads();
        acc += y;
        sd[threadIdx.x] = acc;
        __syncthreads();
    }
    if (threadIdx.x < n) data[threadIdx.x] = acc - x;          // exclusive
}

__global__ void scan_add(int* __restrict__ out, const int* __restrict__ partials, int n) {
    int add = partials[blockIdx.x];
    int base = blockIdx.x * SCAN_TILE + threadIdx.x * SCAN_I;
#pragma unroll
    for (int j = 0; j < SCAN_I; ++j) {
        int idx = base + j;
        if (idx < n) out[idx] += add;
    }
}

__global__ void place_kernel(const int* __restrict__ src, const int* __restrict__ dst,
                             int* __restrict__ cursor, int* __restrict__ sorted_src, int E) {
    int stride = gridDim.x * blockDim.x;
    for (int e = blockIdx.x * blockDim.x + threadIdx.x; e < E; e += stride) {
        int pos = atomicAdd(&cursor[dst[e]], 1);
        sorted_src[pos] = src[e];
    }
}

// ---------------- gather-accumulate (one wave per dst row) ----------------

__global__ void gather_rows(const float* __restrict__ x,
                            const int* __restrict__ row_ptr,
                            const int* __restrict__ sorted_src,
                            float* __restrict__ out, int n) {
    int gtid = blockIdx.x * blockDim.x + threadIdx.x;
    int r = gtid >> 6;           // wave index == dst row
    int lane = gtid & 63;        // lane owns 4 contiguous floats (16B coalesced)
    if (r >= n) return;
    int beg = row_ptr[r];
    int end = row_ptr[r + 1];
    float4 acc = make_float4(0.f, 0.f, 0.f, 0.f);
    for (int i = beg; i < end; ++i) {
        int s = sorted_src[i];   // wave-uniform
        float4 v = *(const float4*)(x + (long long)s * DIM + lane * 4);
        acc.x += v.x; acc.y += v.y; acc.z += v.z; acc.w += v.w;
    }
    float4 o;
    o.x = fmaxf(acc.x, 0.f);
    o.y = fmaxf(acc.y, 0.f);
    o.z = fmaxf(acc.z, 0.f);
    o.w = fmaxf(acc.w, 0.f);
    *(float4*)(out + (long long)r * DIM + lane * 4) = o;       // single write, no atomics
}

// ---------------- fallback (atomic scatter, known-correct) ----------------

template <bool RELU_GATHER>
__global__ void scatter_rows(const float* __restrict__ x,
                             const int* __restrict__ src,
                             const int* __restrict__ dst,
                             float* __restrict__ out, int E) {
    long long tid = (long long)blockIdx.x * blockDim.x + threadIdx.x;
    int e = (int)(tid >> 6);
    int lane = (int)(tid & 63);
    if (e >= E) return;
    int s = src[e];
    int t = dst[e];
    float4 v = *(const float4*)(x + (long long)s * DIM + lane * 4);
    if (RELU_GATHER) {
        v.x = fmaxf(v.x, 0.f); v.y = fmaxf(v.y, 0.f);
        v.z = fmaxf(v.z, 0.f); v.w = fmaxf(v.w, 0.f);
    }
    float* o = out + (long long)t * DIM + (long long)lane * 4;
    atomicAdd(o + 0, v.x); atomicAdd(o + 1, v.y);
    atomicAdd(o + 2, v.z); atomicAdd(o + 3, v.w);
}

__global__ void relu_inplace_f4(float4* __restrict__ x, long long n4) {
    long long stride = (long long)gridDim.x * blockDim.x;
    for (long long i = (long long)blockIdx.x * blockDim.x + threadIdx.x; i < n4; i += stride) {
        float4 v = x[i];
        v.x = fmaxf(v.x, 0.f); v.y = fmaxf(v.y, 0.f);
        v.z = fmaxf(v.z, 0.f); v.w = fmaxf(v.w, 0.f);
        x[i] = v;
    }
}

// ---------------- host ----------------

static void run_hop_csr(const float* x_src, const int* e_src, const int* e_dst,
                        float* out, int n_dst, int E,
                        int* counts, int* row_ptr, int* cursor, int* sorted_src,
                        int* partials, hipStream_t stream) {
    hipMemsetAsync(counts, 0, (size_t)(n_dst + 1) * sizeof(int), stream);
    hist_kernel<<<(E + 255) / 256, 256, 0, stream>>>(e_dst, counts, E);
    int n1 = n_dst + 1;                               // scan n+1 so row_ptr[n] = E
    int nb = (n1 + SCAN_TILE - 1) / SCAN_TILE;        // <= 98 for n=200000
    scan_blocks<<<nb, SCAN_T, 0, stream>>>(counts, row_ptr, partials, n1);
    scan_single<<<1, SCAN_T, 0, stream>>>(partials, nb);
    scan_add<<<nb, SCAN_T, 0, stream>>>(row_ptr, partials, n1);
    hipMemcpyAsync(cursor, row_ptr, (size_t)n_dst * sizeof(int),
                   hipMemcpyDeviceToDevice, stream);
    place_kernel<<<(E + 255) / 256, 256, 0, stream>>>(e_src, e_dst, cursor, sorted_src, E);
    gather_rows<<<(n_dst + 3) / 4, 256, 0, stream>>>(x_src, row_ptr, sorted_src, out, n_dst);
}

extern "C" void kernel_launch(void* const* d_in, const int* in_sizes, int n_in,
                              void* d_out, int out_size, void* d_ws, size_t ws_size,
                              hipStream_t stream) {
    const float* x_paper = (const float*)d_in[0];
    const int* e_pa_src = (const int*)d_in[2];
    const int* e_pa_dst = (const int*)d_in[3];
    const int* e_ap_src = (const int*)d_in[4];
    const int* e_ap_dst = (const int*)d_in[5];

    const int n_paper  = in_sizes[0] / DIM;   // 200000
    const int n_author = in_sizes[1] / DIM;   // 100000
    const int E1 = in_sizes[2];               // 1000000
    const int E2 = in_sizes[4];               // 1000000
    const int n_max = (n_paper > n_author) ? n_paper : n_author;
    const int e_max = (E1 > E2) ? E1 : E2;

    // ws layout
    size_t off = 0;
    auto alloc = [&](size_t bytes) { size_t o = off; off += (bytes + 255) & ~(size_t)255; return o; };
    size_t o_xa1    = alloc((size_t)n_author * DIM * sizeof(float));   // 102.4 MB
    size_t o_counts = alloc((size_t)(n_max + 1) * sizeof(int));
    size_t o_rowptr = alloc((size_t)(n_max + 1) * sizeof(int));
    size_t o_cursor = alloc((size_t)n_max * sizeof(int));
    size_t o_sorted = alloc((size_t)e_max * sizeof(int));
    size_t o_part   = alloc(SCAN_T * sizeof(int));

    char* ws = (char*)d_ws;
    float* x_a1 = (float*)(ws + o_xa1);
    float* x_p2 = (float*)d_out;

    if (off <= ws_size) {
        int* counts  = (int*)(ws + o_counts);
        int* row_ptr = (int*)(ws + o_rowptr);
        int* cursor  = (int*)(ws + o_cursor);
        int* sorted  = (int*)(ws + o_sorted);
        int* part    = (int*)(ws + o_part);
        // hop 1: paper -> author, out = relu(sum)
        run_hop_csr(x_paper, e_pa_src, e_pa_dst, x_a1, n_author, E1,
                    counts, row_ptr, cursor, sorted, part, stream);
        // hop 2: author -> paper, reads relu'd x_a1, out = relu(sum)
        run_hop_csr(x_a1, e_ap_src, e_ap_dst, x_p2, n_paper, E2,
                    counts, row_ptr, cursor, sorted, part, stream);
    } else {
        // fallback: atomic scatter path (passed in round 1)
        const size_t a1_bytes = (size_t)n_author * DIM * sizeof(float);
        const size_t out_bytes = (size_t)out_size * sizeof(float);
        hipMemsetAsync(x_a1 - o_xa1 / sizeof(float), 0, a1_bytes, stream); // x_a1 at ws base
        hipMemsetAsync(x_p2, 0, out_bytes, stream);
        float* a1 = (float*)d_ws;
        const int block = 256;
        {
            long long threads = (long long)E1 * 64;
            int grid = (int)((threads + block - 1) / block);
            scatter_rows<false><<<grid, block, 0, stream>>>(x_paper, e_pa_src, e_pa_dst, a1, E1);
        }
        {
            long long threads = (long long)E2 * 64;
            int grid = (int)((threads + block - 1) / block);
            scatter_rows<true><<<grid, block, 0, stream>>>(a1, e_ap_src, e_ap_dst, x_p2, E2);
        }
        relu_inplace_f4<<<2048, block, 0, stream>>>((float4*)d_out, (long long)out_size / 4);
    }
}

// Round 3
// 549.273 us; speedup vs baseline: 12.2666x; 1.0440x over previous
//
#include <hip/hip_runtime.h>

#define DIM 256
#define SCAN_T 256
#define SCAN_I 8
#define SCAN_TILE (SCAN_T * SCAN_I)
#define BATCH 16      // src-ids prefetched per wave iteration (Poisson(10): 97% rows fit one batch)

// ---------------- CSR build ----------------

__global__ void hist_kernel(const int* __restrict__ dst, int* __restrict__ counts, int E) {
    int stride = gridDim.x * blockDim.x;
    for (int e = blockIdx.x * blockDim.x + threadIdx.x; e < E; e += stride)
        atomicAdd(&counts[dst[e]], 1);
}

// Tiled exclusive scan, 3 kernels. n <= SCAN_T*SCAN_TILE.
__global__ void scan_blocks(const int* __restrict__ in, int* __restrict__ out,
                            int* __restrict__ partials, int n) {
    __shared__ int sd[SCAN_T];
    int base = blockIdx.x * SCAN_TILE + threadIdx.x * SCAN_I;
    int v[SCAN_I];
    int tsum = 0;
#pragma unroll
    for (int j = 0; j < SCAN_I; ++j) {
        int idx = base + j;
        v[j] = (idx < n) ? in[idx] : 0;
        tsum += v[j];
    }
    sd[threadIdx.x] = tsum;
    __syncthreads();
    int acc = tsum;
    for (int ofs = 1; ofs < SCAN_T; ofs <<= 1) {
        int y = (threadIdx.x >= ofs) ? sd[threadIdx.x - ofs] : 0;
        __syncthreads();
        acc += y;
        sd[threadIdx.x] = acc;
        __syncthreads();
    }
    int excl = acc - tsum;
    if (threadIdx.x == SCAN_T - 1) partials[blockIdx.x] = acc;
    int run = excl;
#pragma unroll
    for (int j = 0; j < SCAN_I; ++j) {
        int idx = base + j;
        if (idx < n) out[idx] = run;
        run += v[j];
    }
}

__global__ void scan_single(int* __restrict__ data, int n) {   // n <= SCAN_T
    __shared__ int sd[SCAN_T];
    int x = (threadIdx.x < n) ? data[threadIdx.x] : 0;
    sd[threadIdx.x] = x;
    __syncthreads();
    int acc = x;
    for (int ofs = 1; ofs < SCAN_T; ofs <<= 1) {
        int y = (threadIdx.x >= ofs) ? sd[threadIdx.x - ofs] : 0;
        __syncthreads();
        acc += y;
        sd[threadIdx.x] = acc;
        __syncthreads();
    }
    if (threadIdx.x < n) data[threadIdx.x] = acc - x;
}

// adds block partials AND writes the cursor copy (fused, saves a D2D memcpy)
__global__ void scan_add_copy(int* __restrict__ out, int* __restrict__ cursor,
                              const int* __restrict__ partials, int n) {
    int add = partials[blockIdx.x];
    int base = blockIdx.x * SCAN_TILE + threadIdx.x * SCAN_I;
#pragma unroll
    for (int j = 0; j < SCAN_I; ++j) {
        int idx = base + j;
        if (idx < n) {
            int v = out[idx] + add;
            out[idx] = v;
            if (idx < n - 1) cursor[idx] = v;   // cursor sized n-1 (= n_dst)
        }
    }
}

__global__ void place_kernel(const int* __restrict__ src, const int* __restrict__ dst,
                             int* __restrict__ cursor, int* __restrict__ sorted_src, int E) {
    int stride = gridDim.x * blockDim.x;
    for (int e = blockIdx.x * blockDim.x + threadIdx.x; e < E; e += stride) {
        int pos = atomicAdd(&cursor[dst[e]], 1);
        sorted_src[pos] = src[e];
    }
}

// ---------------- gather-accumulate (one wave per dst row, batched MLP) ----------------

__global__ void gather_rows(const float* __restrict__ x,
                            const int* __restrict__ row_ptr,
                            const int* __restrict__ sorted_src,
                            float* __restrict__ out, int n) {
    int gtid = blockIdx.x * blockDim.x + threadIdx.x;
    int r = gtid >> 6;           // wave index == dst row
    int lane = gtid & 63;        // lane owns 4 contiguous floats (16B coalesced)
    if (r >= n) return;
    int beg = row_ptr[r];
    int end = row_ptr[r + 1];
    float4 acc = make_float4(0.f, 0.f, 0.f, 0.f);
    for (int i = beg; i < end; i += BATCH) {
        int cnt = end - i;
        cnt = (cnt < BATCH) ? cnt : BATCH;
        // lane j holds src id of edge i+j (clamped so every lane is valid)
        int li = (lane < cnt) ? lane : (cnt - 1);
        int sid = sorted_src[i + li];
#pragma unroll
        for (int j = 0; j < BATCH; ++j) {
            if (j >= cnt) break;                       // wave-uniform branch
            int s = __builtin_amdgcn_readlane(sid, j); // SGPR broadcast
            const float4* row = (const float4*)(x + (long long)s * DIM);
            float4 v = row[lane];                      // 1KB/wave, coalesced
            acc.x += v.x; acc.y += v.y; acc.z += v.z; acc.w += v.w;
        }
    }
    float4 o;
    o.x = fmaxf(acc.x, 0.f);
    o.y = fmaxf(acc.y, 0.f);
    o.z = fmaxf(acc.z, 0.f);
    o.w = fmaxf(acc.w, 0.f);
    *(float4*)(out + (long long)r * DIM + lane * 4) = o;   // single write, no atomics
}

// ---------------- fallback (atomic scatter, known-correct) ----------------

template <bool RELU_GATHER>
__global__ void scatter_rows(const float* __restrict__ x,
                             const int* __restrict__ src,
                             const int* __restrict__ dst,
                             float* __restrict__ out, int E) {
    long long tid = (long long)blockIdx.x * blockDim.x + threadIdx.x;
    int e = (int)(tid >> 6);
    int lane = (int)(tid & 63);
    if (e >= E) return;
    int s = src[e];
    int t = dst[e];
    float4 v = *(const float4*)(x + (long long)s * DIM + lane * 4);
    if (RELU_GATHER) {
        v.x = fmaxf(v.x, 0.f); v.y = fmaxf(v.y, 0.f);
        v.z = fmaxf(v.z, 0.f); v.w = fmaxf(v.w, 0.f);
    }
    float* o = out + (long long)t * DIM + (long long)lane * 4;
    atomicAdd(o + 0, v.x); atomicAdd(o + 1, v.y);
    atomicAdd(o + 2, v.z); atomicAdd(o + 3, v.w);
}

__global__ void relu_inplace_f4(float4* __restrict__ x, long long n4) {
    long long stride = (long long)gridDim.x * blockDim.x;
    for (long long i = (long long)blockIdx.x * blockDim.x + threadIdx.x; i < n4; i += stride) {
        float4 v = x[i];
        v.x = fmaxf(v.x, 0.f); v.y = fmaxf(v.y, 0.f);
        v.z = fmaxf(v.z, 0.f); v.w = fmaxf(v.w, 0.f);
        x[i] = v;
    }
}

// ---------------- host ----------------

static void run_hop_csr(const float* x_src, const int* e_src, const int* e_dst,
                        float* out, int n_dst, int E,
                        int* counts, int* row_ptr, int* cursor, int* sorted_src,
                        int* partials, hipStream_t stream) {
    hipMemsetAsync(counts, 0, (size_t)(n_dst + 1) * sizeof(int), stream);
    hist_kernel<<<(E + 255) / 256, 256, 0, stream>>>(e_dst, counts, E);
    int n1 = n_dst + 1;                               // scan n+1 so row_ptr[n] = E
    int nb = (n1 + SCAN_TILE - 1) / SCAN_TILE;
    scan_blocks<<<nb, SCAN_T, 0, stream>>>(counts, row_ptr, partials, n1);
    scan_single<<<1, SCAN_T, 0, stream>>>(partials, nb);
    scan_add_copy<<<nb, SCAN_T, 0, stream>>>(row_ptr, cursor, partials, n1);
    place_kernel<<<(E + 255) / 256, 256, 0, stream>>>(e_src, e_dst, cursor, sorted_src, E);
    gather_rows<<<(n_dst + 3) / 4, 256, 0, stream>>>(x_src, row_ptr, sorted_src, out, n_dst);
}

extern "C" void kernel_launch(void* const* d_in, const int* in_sizes, int n_in,
                              void* d_out, int out_size, void* d_ws, size_t ws_size,
                              hipStream_t stream) {
    const float* x_paper = (const float*)d_in[0];
    const int* e_pa_src = (const int*)d_in[2];
    const int* e_pa_dst = (const int*)d_in[3];
    const int* e_ap_src = (const int*)d_in[4];
    const int* e_ap_dst = (const int*)d_in[5];

    const int n_paper  = in_sizes[0] / DIM;   // 200000
    const int n_author = in_sizes[1] / DIM;   // 100000
    const int E1 = in_sizes[2];               // 1000000
    const int E2 = in_sizes[4];               // 1000000
    const int n_max = (n_paper > n_author) ? n_paper : n_author;
    const int e_max = (E1 > E2) ? E1 : E2;

    // ws layout (identical footprint to the proven round-2 layout)
    size_t off = 0;
    auto alloc = [&](size_t bytes) { size_t o = off; off += (bytes + 255) & ~(size_t)255; return o; };
    size_t o_xa1    = alloc((size_t)n_author * DIM * sizeof(float));   // 102.4 MB
    size_t o_counts = alloc((size_t)(n_max + 1) * sizeof(int));
    size_t o_rowptr = alloc((size_t)(n_max + 1) * sizeof(int));
    size_t o_cursor = alloc((size_t)n_max * sizeof(int));
    size_t o_sorted = alloc((size_t)e_max * sizeof(int));
    size_t o_part   = alloc(SCAN_T * sizeof(int));

    char* ws = (char*)d_ws;
    float* x_a1 = (float*)(ws + o_xa1);
    float* x_p2 = (float*)d_out;

    if (off <= ws_size) {
        int* counts  = (int*)(ws + o_counts);
        int* row_ptr = (int*)(ws + o_rowptr);
        int* cursor  = (int*)(ws + o_cursor);
        int* sorted  = (int*)(ws + o_sorted);
        int* part    = (int*)(ws + o_part);
        // hop 1: paper -> author, out = relu(sum)
        run_hop_csr(x_paper, e_pa_src, e_pa_dst, x_a1, n_author, E1,
                    counts, row_ptr, cursor, sorted, part, stream);
        // hop 2: author -> paper, reads relu'd x_a1, out = relu(sum)
        run_hop_csr(x_a1, e_ap_src, e_ap_dst, x_p2, n_paper, E2,
                    counts, row_ptr, cursor, sorted, part, stream);
    } else {
        // fallback: atomic scatter path (passed in round 1)
        float* a1 = (float*)d_ws;
        hipMemsetAsync(a1, 0, (size_t)n_author * DIM * sizeof(float), stream);
        hipMemsetAsync(x_p2, 0, (size_t)out_size * sizeof(float), stream);
        const int block = 256;
        {
            long long threads = (long long)E1 * 64;
            int grid = (int)((threads + block - 1) / block);
            scatter_rows<false><<<grid, block, 0, stream>>>(x_paper, e_pa_src, e_pa_dst, a1, E1);
        }
        {
            long long threads = (long long)E2 * 64;
            int grid = (int)((threads + block - 1) / block);
            scatter_rows<true><<<grid, block, 0, stream>>>(a1, e_ap_src, e_ap_dst, x_p2, E2);
        }
        relu_inplace_f4<<<2048, block, 0, stream>>>((float4*)d_out, (long long)out_size / 4);
    }
}

// Round 4
// 498.025 us; speedup vs baseline: 13.5288x; 1.1029x over previous
//
#include <hip/hip_runtime.h>

#define DIM 256
#define SCAN_T 256
#define SCAN_I 8
#define SCAN_TILE (SCAN_T * SCAN_I)
#define BATCH 16

typedef float f32x4 __attribute__((ext_vector_type(4)));
typedef unsigned int u32;
typedef unsigned short u16;

__device__ __forceinline__ u16 f32_to_bf16_rne(float f) {
    u32 u = __float_as_uint(f);
    u32 r = (u + 0x7FFFu + ((u >> 16) & 1u)) >> 16;   // round-to-nearest-even
    return (u16)r;
}

// ---------------- f32 -> bf16 streaming convert (NT load: read-once) ----------------

__global__ void convert_f32_bf16(const float* __restrict__ in, u16* __restrict__ out, long long n4) {
    long long stride = (long long)gridDim.x * blockDim.x;
    for (long long i = (long long)blockIdx.x * blockDim.x + threadIdx.x; i < n4; i += stride) {
        f32x4 v = __builtin_nontemporal_load((const f32x4*)in + i);
        ushort4 o;
        o.x = f32_to_bf16_rne(v.x);
        o.y = f32_to_bf16_rne(v.y);
        o.z = f32_to_bf16_rne(v.z);
        o.w = f32_to_bf16_rne(v.w);
        *((ushort4*)out + i) = o;   // re-read by gather1: keep cached
    }
}

// ---------------- CSR build: both relations in one pass ----------------

__global__ void hist2(const int* __restrict__ dA, const int* __restrict__ dB,
                      int* __restrict__ cA, int* __restrict__ cB, int E1, int Etot) {
    int stride = gridDim.x * blockDim.x;
    for (int e = blockIdx.x * blockDim.x + threadIdx.x; e < Etot; e += stride) {
        if (e < E1) atomicAdd(&cA[dA[e]], 1);
        else        atomicAdd(&cB[dB[e - E1]], 1);
    }
}

// segmented exclusive scan over [counts_A(n1A) | counts_B(n1B)], partials per segment
__global__ void scan_blocks2(const int* __restrict__ in, int* __restrict__ out,
                             int* __restrict__ parts, int n1A, int nbA, int n1B) {
    __shared__ int sd[SCAN_T];
    int seg = (blockIdx.x >= nbA) ? 1 : 0;
    int lb  = seg ? (blockIdx.x - nbA) : blockIdx.x;
    int gbase = seg ? n1A : 0;
    int n = seg ? n1B : n1A;
    int* partials = parts + seg * 128;
    int base = lb * SCAN_TILE + threadIdx.x * SCAN_I;
    int v[SCAN_I];
    int tsum = 0;
#pragma unroll
    for (int j = 0; j < SCAN_I; ++j) {
        int idx = base + j;
        v[j] = (idx < n) ? in[gbase + idx] : 0;
        tsum += v[j];
    }
    sd[threadIdx.x] = tsum;
    __syncthreads();
    int acc = tsum;
    for (int ofs = 1; ofs < SCAN_T; ofs <<= 1) {
        int y = (threadIdx.x >= ofs) ? sd[threadIdx.x - ofs] : 0;
        __syncthreads();
        acc += y;
        sd[threadIdx.x] = acc;
        __syncthreads();
    }
    int excl = acc - tsum;
    if (threadIdx.x == SCAN_T - 1) partials[lb] = acc;
    int run = excl;
#pragma unroll
    for (int j = 0; j < SCAN_I; ++j) {
        int idx = base + j;
        if (idx < n) out[gbase + idx] = run;
        run += v[j];
    }
}

__global__ void scan_single2(int* __restrict__ parts, int nbA, int nbB) {
    __shared__ int sd[SCAN_T];
    int* p = parts + blockIdx.x * 128;
    int n = blockIdx.x ? nbB : nbA;
    int x = (threadIdx.x < n) ? p[threadIdx.x] : 0;
    sd[threadIdx.x] = x;
    __syncthreads();
    int acc = x;
    for (int ofs = 1; ofs < SCAN_T; ofs <<= 1) {
        int y = (threadIdx.x >= ofs) ? sd[threadIdx.x - ofs] : 0;
        __syncthreads();
        acc += y;
        sd[threadIdx.x] = acc;
        __syncthreads();
    }
    if (threadIdx.x < n) p[threadIdx.x] = acc - x;
}

// add block partials + write the cursor copy (cursor_A at [0,nA), cursor_B at [nA,...))
__global__ void scan_add_copy2(int* __restrict__ rp, int* __restrict__ cursor,
                               const int* __restrict__ parts,
                               int n1A, int nbA, int n1B, int nA) {
    int seg = (blockIdx.x >= nbA) ? 1 : 0;
    int lb  = seg ? (blockIdx.x - nbA) : blockIdx.x;
    int gbase = seg ? n1A : 0;
    int n = seg ? n1B : n1A;
    int cbase = seg ? nA : 0;
    int add = parts[seg * 128 + lb];
    int base = lb * SCAN_TILE + threadIdx.x * SCAN_I;
#pragma unroll
    for (int j = 0; j < SCAN_I; ++j) {
        int idx = base + j;
        if (idx < n) {
            int v = rp[gbase + idx] + add;
            rp[gbase + idx] = v;
            if (idx < n - 1) cursor[cbase + idx] = v;
        }
    }
}

__global__ void place2(const int* __restrict__ sA, const int* __restrict__ dA,
                       const int* __restrict__ sB, const int* __restrict__ dB,
                       int* __restrict__ curA, int* __restrict__ curB,
                       int* __restrict__ sortA, int* __restrict__ sortB,
                       int E1, int Etot) {
    int stride = gridDim.x * blockDim.x;
    for (int e = blockIdx.x * blockDim.x + threadIdx.x; e < Etot; e += stride) {
        if (e < E1) {
            int p = atomicAdd(&curA[dA[e]], 1);
            sortA[p] = sA[e];
        } else {
            int e2 = e - E1;
            int p = atomicAdd(&curB[dB[e2]], 1);
            sortB[p] = sB[e2];
        }
    }
}

// ---------------- gather-accumulate (one wave per dst row, batched MLP) ----------------
// SBF: source rows are bf16 (512B) vs f32 (1KB). DBF: output bf16 (relu+RNE pack) vs f32 NT.

template <bool SBF, bool DBF>
__global__ void gather_rows(const void* __restrict__ xv,
                            const int* __restrict__ row_ptr,
                            const int* __restrict__ sorted_src,
                            void* __restrict__ outv, int n) {
    int gtid = blockIdx.x * blockDim.x + threadIdx.x;
    int r = gtid >> 6;           // wave index == dst row
    int lane = gtid & 63;
    if (r >= n) return;
    int beg = row_ptr[r];
    int end = row_ptr[r + 1];
    float ax = 0.f, ay = 0.f, az = 0.f, aw = 0.f;
    for (int i = beg; i < end; i += BATCH) {
        int cnt = end - i;
        cnt = (cnt < BATCH) ? cnt : BATCH;
        int li = (lane < cnt) ? lane : (cnt - 1);
        int sid = sorted_src[i + li];
#pragma unroll
        for (int j = 0; j < BATCH; ++j) {
            if (j >= cnt) break;                       // wave-uniform
            int s = __builtin_amdgcn_readlane(sid, j); // SGPR broadcast
            if (SBF) {
                const uint2* row = (const uint2*)((const u16*)xv + (long long)s * DIM);
                uint2 v = row[lane];                   // 8B/lane, 512B/wave coalesced
                ax += __uint_as_float(v.x << 16);
                ay += __uint_as_float(v.x & 0xFFFF0000u);
                az += __uint_as_float(v.y << 16);
                aw += __uint_as_float(v.y & 0xFFFF0000u);
            } else {
                const float4* row = (const float4*)((const float*)xv + (long long)s * DIM);
                float4 v = row[lane];                  // 16B/lane, 1KB/wave coalesced
                ax += v.x; ay += v.y; az += v.z; aw += v.w;
            }
        }
    }
    ax = fmaxf(ax, 0.f); ay = fmaxf(ay, 0.f); az = fmaxf(az, 0.f); aw = fmaxf(aw, 0.f);
    if (DBF) {
        ushort4 o;
        o.x = f32_to_bf16_rne(ax); o.y = f32_to_bf16_rne(ay);
        o.z = f32_to_bf16_rne(az); o.w = f32_to_bf16_rne(aw);
        *((ushort4*)outv + (long long)r * (DIM / 4) + lane) = o;   // re-read next hop: cached
    } else {
        f32x4 o = { ax, ay, az, aw };
        // never re-read: NT store keeps the 51MB bf16 table L2/L3-resident
        __builtin_nontemporal_store(o, (f32x4*)outv + (long long)r * (DIM / 4) + lane);
    }
}

// ---------------- host ----------------

extern "C" void kernel_launch(void* const* d_in, const int* in_sizes, int n_in,
                              void* d_out, int out_size, void* d_ws, size_t ws_size,
                              hipStream_t stream) {
    const float* x_paper = (const float*)d_in[0];
    const int* e_pa_src = (const int*)d_in[2];
    const int* e_pa_dst = (const int*)d_in[3];
    const int* e_ap_src = (const int*)d_in[4];
    const int* e_ap_dst = (const int*)d_in[5];

    const int n_paper  = in_sizes[0] / DIM;   // 200000
    const int n_author = in_sizes[1] / DIM;   // 100000
    const int E1 = in_sizes[2];               // 1000000 (paper->author)
    const int E2 = in_sizes[4];               // 1000000 (author->paper)
    const int Etot = E1 + E2;
    const int n1A = n_author + 1;
    const int n1B = n_paper + 1;
    const int nbA = (n1A + SCAN_TILE - 1) / SCAN_TILE;   // 49
    const int nbB = (n1B + SCAN_TILE - 1) / SCAN_TILE;   // 98  (<=128)

    // ---- workspace layout ----
    size_t off = 0;
    auto alloc = [&](size_t bytes) { size_t o = off; off += (bytes + 255) & ~(size_t)255; return o; };
    // Tier A includes a bf16 copy of x_paper; Tier B drops it.
    size_t o_xpbf   = alloc((size_t)n_paper * DIM * sizeof(u16));     // 102.4 MB
    size_t tierB_mark = off;  // everything below is needed by both tiers
    size_t o_xa1    = alloc((size_t)n_author * DIM * sizeof(u16));    // 51.2 MB
    size_t o_counts = alloc((size_t)(n1A + n1B) * sizeof(int));
    size_t o_rowptr = alloc((size_t)(n1A + n1B) * sizeof(int));
    size_t o_cursor = alloc((size_t)(n_author + n_paper) * sizeof(int));
    size_t o_sorted = alloc((size_t)Etot * sizeof(int));
    size_t o_part   = alloc(256 * sizeof(int));
    size_t totalA = off;
    size_t needB = off - tierB_mark;   // tier B packs from ws base (just shift all down)

    char* ws = (char*)d_ws;
    bool tierA = (totalA <= ws_size);
    size_t shift = tierA ? 0 : o_xpbf;  // tier B: drop xpbf, slide everything to base
    if (!tierA && needB > ws_size) return;  // nothing fits (ws known >= 109MB, won't happen)

    u16* xpbf     = (u16*)(ws + o_xpbf   - 0);       // tier A only
    u16* x_a1     = (u16*)(ws + o_xa1    - shift);
    int* counts   = (int*)(ws + o_counts - shift);
    int* row_ptr  = (int*)(ws + o_rowptr - shift);
    int* cursor   = (int*)(ws + o_cursor - shift);
    int* sorted   = (int*)(ws + o_sorted - shift);
    int* parts    = (int*)(ws + o_part   - shift);

    int* countsA = counts;            int* countsB = counts + n1A;
    int* curA    = cursor;            int* curB    = cursor + n_author;
    int* sortA   = sorted;            int* sortB   = sorted + E1;
    int* rpA     = row_ptr;           int* rpB     = row_ptr + n1A;
    float* x_p2  = (float*)d_out;

    hipMemsetAsync(counts, 0, (size_t)(n1A + n1B) * sizeof(int), stream);
    if (tierA) {
        long long n4 = (long long)n_paper * DIM / 4;
        convert_f32_bf16<<<2048, 256, 0, stream>>>(x_paper, xpbf, n4);
    }
    hist2<<<4096, 256, 0, stream>>>(e_pa_dst, e_ap_dst, countsA, countsB, E1, Etot);
    scan_blocks2<<<nbA + nbB, SCAN_T, 0, stream>>>(counts, row_ptr, parts, n1A, nbA, n1B);
    scan_single2<<<2, SCAN_T, 0, stream>>>(parts, nbA, nbB);
    scan_add_copy2<<<nbA + nbB, SCAN_T, 0, stream>>>(row_ptr, cursor, parts, n1A, nbA, n1B, n_author);
    place2<<<4096, 256, 0, stream>>>(e_pa_src, e_pa_dst, e_ap_src, e_ap_dst,
                                     curA, curB, sortA, sortB, E1, Etot);
    // hop 1: paper -> author, out = bf16(relu(sum))
    if (tierA)
        gather_rows<true,  true><<<(n_author + 3) / 4, 256, 0, stream>>>(xpbf, rpA, sortA, x_a1, n_author);
    else
        gather_rows<false, true><<<(n_author + 3) / 4, 256, 0, stream>>>(x_paper, rpA, sortA, x_a1, n_author);
    // hop 2: author -> paper, out = f32 relu(sum), NT stores
    gather_rows<true, false><<<(n_paper + 3) / 4, 256, 0, stream>>>(x_a1, rpB, sortB, x_p2, n_paper);
}